// Round 1
// baseline (86.457 us; speedup 1.0000x reference)
//
#include <hip/hip_runtime.h>

// vLoss_36112085024869:
// The reference computes log_softmax over axis=1 of a (N,1,W,H) tensor — a
// SINGLETON axis. log_softmax(x) = x - logsumexp(x) = 0 identically for any
// finite x (pred is in {0..3}, always finite). Hence picked == 0 everywhere
// and loss == -0.0 regardless of inputs. All the einsum/distance/argmin work
// is dead code. The optimal kernel is a single scalar store.
//
// d_out is re-poisoned to 0xAA before every timed launch, so we must write
// it on every call (which we do — no static guards).

__global__ void vLoss_36112085024869_kernel(float* __restrict__ out) {
    if (threadIdx.x == 0) {
        out[0] = -0.0f;   // matches reference's -jnp.sum(zeros) == -0.0
    }
}

extern "C" void kernel_launch(void* const* d_in, const int* in_sizes, int n_in,
                              void* d_out, int out_size, void* d_ws, size_t ws_size,
                              hipStream_t stream) {
    (void)d_in; (void)in_sizes; (void)n_in; (void)out_size; (void)d_ws; (void)ws_size;
    vLoss_36112085024869_kernel<<<dim3(1), dim3(64), 0, stream>>>((float*)d_out);
}